// Round 2
// baseline (628.305 us; speedup 1.0000x reference)
//
#include <hip/hip_runtime.h>
#include <math.h>

// VQ-VAE quantize: z [8,4096,512] f32, embed_w [1024,512] f32
// out = concat(z_q, diff, ind-as-f32)

#define D_DIM   512
#define K_CODES 1024
#define N_TOK   32768

#define BM 32         // z-rows per block
#define BN 512        // codes per tile (2 tiles cover 1024)
#define BK 8          // k per round
#define NROUNDS 128   // (K_CODES/BN) * (D_DIM/BK)

// ws layout: [0, 2MB) ewT fp32 [512][1024]; [2MB, +4KB) e2[1024]

// ---------------- ew transpose: ewT[k][code] = ew[code][k] ----------------
__global__ __launch_bounds__(256) void vq_prep_kernel(const float* __restrict__ ew,
                                                      float* __restrict__ ewT) {
    __shared__ float tile[64][65];
    const int t = threadIdx.x;
    const int r = t >> 4;     // 0..15
    const int c = t & 15;     // 0..15
    const int code0 = blockIdx.x * 64;  // 16 blocks
    const int k0    = blockIdx.y * 64;  // 8 blocks
#pragma unroll
    for (int q = 0; q < 4; ++q) {
        float4 v = *(const float4*)&ew[(size_t)(code0 + r + 16 * q) * D_DIM + k0 + c * 4];
        tile[r + 16 * q][c * 4 + 0] = v.x;
        tile[r + 16 * q][c * 4 + 1] = v.y;
        tile[r + 16 * q][c * 4 + 2] = v.z;
        tile[r + 16 * q][c * 4 + 3] = v.w;
    }
    __syncthreads();
#pragma unroll
    for (int q = 0; q < 4; ++q) {
        float4 v;
        v.x = tile[c * 4 + 0][r + 16 * q];
        v.y = tile[c * 4 + 1][r + 16 * q];
        v.z = tile[c * 4 + 2][r + 16 * q];
        v.w = tile[c * 4 + 3][r + 16 * q];
        *(float4*)&ewT[(size_t)(k0 + r + 16 * q) * K_CODES + code0 + c * 4] = v;
    }
}

// ---------------- e2 = ||e_k||^2 ------------------------------------------
__global__ __launch_bounds__(256) void vq_e2_kernel(const float* __restrict__ ew,
                                                    float* __restrict__ e2) {
    const int w    = threadIdx.x >> 6;
    const int lane = threadIdx.x & 63;
    const int cc   = blockIdx.x * 4 + w;
    const float* row = &ew[(size_t)cc * D_DIM];
    float s = 0.0f;
#pragma unroll
    for (int i = 0; i < D_DIM / 64; ++i) {
        float v = row[lane + i * 64];
        s = fmaf(v, v, s);
    }
#pragma unroll
    for (int off = 32; off > 0; off >>= 1) s += __shfl_xor(s, off, 64);
    if (lane == 0) e2[cc] = s;
}

// ---------------- argmin over codes (fp32, conflict-free, dbuf) -----------
__global__ __launch_bounds__(256) void vq_argmin_kernel(
    const float* __restrict__ z, const float* __restrict__ ewT,
    const float* __restrict__ e2, float* __restrict__ indf) {
    __shared__ float As[2][BK][BM];    // swizzled cols: elem (k,m) at [k][m ^ (((k>>2)&1)<<4)]
    __shared__ float Bs[2][BK][BN];

    const int t    = threadIdx.x;
    const int lane = t & 63;
    const int wv   = t >> 6;           // wave id = row-group
    const int row0 = blockIdx.x * BM;

    // Bs staging coords: 8 rows x 128 float4 = 1024 float4 / 256 thr = 4 each
    const int bkk0 = t >> 7;           // 0..1
    const int bc4  = t & 127;          // float4 column
    // As staging coords (t < 64): 32 rows, 2 lanes/row
    const int am = t >> 1;             // 0..31
    const int ak = (t & 1) * 4;        // 0 or 4
    const int gg = (ak & 4) << 2;      // swizzle: 0 or 16

    float best[8], acc[8][8];
    int   bidx[8];
#pragma unroll
    for (int i = 0; i < 8; ++i) { best[i] = INFINITY; bidx[i] = 0; }
#pragma unroll
    for (int i = 0; i < 8; ++i)
#pragma unroll
        for (int j = 0; j < 8; ++j) acc[i][j] = 0.0f;

    // prologue: stage tile 0 into buf 0
    {
        float4 b4[4];
#pragma unroll
        for (int u = 0; u < 4; ++u) {
            const int kk = u * 2 + bkk0;
            b4[u] = *(const float4*)&ewT[(size_t)kk * K_CODES + bc4 * 4];
        }
        float4 a4 = {0, 0, 0, 0};
        if (t < 64) a4 = *(const float4*)&z[(size_t)(row0 + am) * D_DIM + ak];
#pragma unroll
        for (int u = 0; u < 4; ++u) {
            const int kk = u * 2 + bkk0;
            *(float4*)&Bs[0][kk][bc4 * 4] = b4[u];
        }
        if (t < 64) {
#pragma unroll
            for (int i = 0; i < 4; ++i) As[0][ak + i][am ^ gg] = (&a4.x)[i];
        }
    }
    __syncthreads();

    for (int T = 0; T < NROUNDS; ++T) {
        const int cur = T & 1;
        float4 b4[4];
        float4 a4 = {0, 0, 0, 0};
        const int Tn = T + 1;
        if (Tn < NROUNDS) {
            const int k0n = (Tn & 63) * BK;
            const int n0n = (Tn >> 6) * BN;
#pragma unroll
            for (int u = 0; u < 4; ++u) {
                const int kk = u * 2 + bkk0;
                b4[u] = *(const float4*)&ewT[(size_t)(k0n + kk) * K_CODES + n0n + bc4 * 4];
            }
            if (t < 64) a4 = *(const float4*)&z[(size_t)(row0 + am) * D_DIM + k0n + ak];
        }

        // compute: 8 k-steps x 64 FMA
#pragma unroll
        for (int k = 0; k < BK; ++k) {
            const int g     = (k & 4) << 2;       // ((k>>2)&1)<<4
            const int mbase = (wv * 8) ^ g;       // wave-uniform -> broadcast reads
            float av[8], bv[8];
            *(float4*)&av[0] = *(const float4*)&As[cur][k][mbase];
            *(float4*)&av[4] = *(const float4*)&As[cur][k][mbase + 4];
            *(float4*)&bv[0] = *(const float4*)&Bs[cur][k][lane * 4];         // lane*16B contiguous
            *(float4*)&bv[4] = *(const float4*)&Bs[cur][k][256 + lane * 4];
#pragma unroll
            for (int i = 0; i < 8; ++i)
#pragma unroll
                for (int j = 0; j < 8; ++j)
                    acc[i][j] = fmaf(av[i], bv[j], acc[i][j]);
        }

        // write next tile into the other buffer (loads had full compute to land)
        if (Tn < NROUNDS) {
#pragma unroll
            for (int u = 0; u < 4; ++u) {
                const int kk = u * 2 + bkk0;
                *(float4*)&Bs[cur ^ 1][kk][bc4 * 4] = b4[u];
            }
            if (t < 64) {
#pragma unroll
                for (int i = 0; i < 4; ++i) As[cur ^ 1][ak + i][am ^ gg] = (&a4.x)[i];
            }
        }

        // per-code-tile epilogue: fold e2, update running best (codes ascending)
        if ((T & 63) == 63) {
            const int n0 = (T >> 6) * BN;
            float4 c0 = *(const float4*)&e2[n0 + lane * 4];
            float4 c1 = *(const float4*)&e2[n0 + 256 + lane * 4];
            float e2v[8] = {c0.x, c0.y, c0.z, c0.w, c1.x, c1.y, c1.z, c1.w};
#pragma unroll
            for (int j = 0; j < 8; ++j) {
                const int n = n0 + (j < 4 ? lane * 4 + j : 256 + lane * 4 + (j - 4));
#pragma unroll
                for (int i = 0; i < 8; ++i) {
                    const float s = fmaf(-2.0f, acc[i][j], e2v[j]);
                    if (s < best[i]) { best[i] = s; bidx[i] = n; }
                }
            }
#pragma unroll
            for (int i = 0; i < 8; ++i)
#pragma unroll
                for (int j = 0; j < 8; ++j) acc[i][j] = 0.0f;
        }
        __syncthreads();
    }

    // per-wave lexicographic (val, idx) reduce across 64 lanes
#pragma unroll
    for (int i = 0; i < 8; ++i) {
        float v  = best[i];
        int   ix = bidx[i];
#pragma unroll
        for (int off = 32; off > 0; off >>= 1) {
            float vv = __shfl_xor(v, off, 64);
            int   ii = __shfl_xor(ix, off, 64);
            if (vv < v || (vv == v && ii < ix)) { v = vv; ix = ii; }
        }
        if (lane == 0) indf[row0 + wv * 8 + i] = (float)ix;
    }
}

// ---------------- outputs: z_q, diff --------------------------------------
__global__ __launch_bounds__(256) void vq_out_kernel(
    const float* __restrict__ z, const float* __restrict__ ew,
    const float* __restrict__ indf, float* __restrict__ zq,
    float* __restrict__ diff) {
    const int w    = threadIdx.x >> 6;
    const int lane = threadIdx.x & 63;
    const int row  = blockIdx.x * 4 + w;
    const int c    = (int)indf[row];

    const float4* z4 = (const float4*)&z[(size_t)row * D_DIM];
    const float4* e4 = (const float4*)&ew[(size_t)c * D_DIM];
    float4* q4 = (float4*)&zq[(size_t)row * D_DIM];
    float4* d4 = (float4*)&diff[(size_t)row * D_DIM];

#pragma unroll
    for (int v = 0; v < 2; ++v) {
        const int i = v * 64 + lane;
        const float4 zv = z4[i];
        const float4 ev = e4[i];
        float4 qv, dv;
        float ax = ev.x - zv.x, ay = ev.y - zv.y, az = ev.z - zv.z, aw = ev.w - zv.w;
        qv.x = zv.x + ax; qv.y = zv.y + ay; qv.z = zv.z + az; qv.w = zv.w + aw;
        dv.x = 0.5f * (ax * ax); dv.y = 0.5f * (ay * ay);
        dv.z = 0.5f * (az * az); dv.w = 0.5f * (aw * aw);
        q4[i] = qv;
        d4[i] = dv;
    }
}

extern "C" void kernel_launch(void* const* d_in, const int* in_sizes, int n_in,
                              void* d_out, int out_size, void* d_ws, size_t ws_size,
                              hipStream_t stream) {
    const float* z  = (const float*)d_in[0];
    const float* ew = (const float*)d_in[1];
    float* out  = (float*)d_out;
    float* zq   = out;
    float* diff = out + (size_t)N_TOK * D_DIM;
    float* indf = out + (size_t)2 * N_TOK * D_DIM;

    float* ewT = (float*)d_ws;                               // 2 MB
    float* e2  = (float*)d_ws + (size_t)D_DIM * K_CODES;     // 4 KB

    hipLaunchKernelGGL(vq_prep_kernel, dim3(16, 8), dim3(256), 0, stream, ew, ewT);
    hipLaunchKernelGGL(vq_e2_kernel, dim3(K_CODES / 4), dim3(256), 0, stream, ew, e2);
    hipLaunchKernelGGL(vq_argmin_kernel, dim3(N_TOK / BM), dim3(256), 0, stream,
                       z, ewT, e2, indf);
    hipLaunchKernelGGL(vq_out_kernel, dim3(N_TOK / 4), dim3(256), 0, stream,
                       z, ew, indf, zq, diff);
}

// Round 3
// 237.279 us; speedup vs baseline: 2.6480x; 2.6480x over previous
//
#include <hip/hip_runtime.h>
#include <math.h>

// VQ-VAE quantize: z [8,4096,512] f32, embed_w [1024,512] f32
// out = concat(z_q [16.78M], diff [16.78M], ind [32768] as f32)
//
// Strategy: split-precision bf16 MFMA for the distance matmul.
//   z = zhi + zlo, e = ehi + elo (bf16 RNE splits)
//   dot ~= zhi*ehi + zhi*elo + zlo*ehi   (3 MFMA k-steps per physical k-tile)
//   score = ||e||^2 - 2*dot (row-constant ||z||^2 dropped; argmin invariant)
// Scratch (ehi/elo/e2/partials ~4MB) lives in d_out's z_q region, which the
// final output kernel overwrites last.

#define D_DIM   512
#define K_CODES 1024
#define N_TOK   32768

#define BM   128
#define BN   128
#define BKP  32            // physical f32 k per staged tile
#define NKT  (D_DIM / BKP) // 16
#define LDSB 144           // bytes per LDS row: 64 eff bf16 (128B) + 16B pad (16*9)

typedef __attribute__((ext_vector_type(8))) short bf16x8;
typedef __attribute__((ext_vector_type(4))) float f32x4;

// exact RNE f32 -> bf16-bits split helpers
__device__ __forceinline__ unsigned short bf16_rne(float f) {
    unsigned int u = __float_as_uint(f);
    return (unsigned short)((u + 0x7FFFu + ((u >> 16) & 1u)) >> 16);
}
__device__ __forceinline__ float bf16_to_f32(unsigned short b) {
    return __uint_as_float(((unsigned int)b) << 16);
}

// ---------------- prep: ehi/elo bf16 + e2 f32 -----------------------------
__global__ __launch_bounds__(256) void vq_prep(const float* __restrict__ ew,
                                               unsigned short* __restrict__ ehi,
                                               unsigned short* __restrict__ elo,
                                               float* __restrict__ e2) {
    const int wv = threadIdx.x >> 6, lane = threadIdx.x & 63;
    const int code = blockIdx.x * 4 + wv;          // grid 256
    const float* row = ew + (size_t)code * D_DIM;
    float s = 0.0f;
#pragma unroll
    for (int h = 0; h < 2; ++h) {
        const int c = h * 256 + lane * 4;
        float4 v = *(const float4*)(row + c);
        float f[4] = {v.x, v.y, v.z, v.w};
        unsigned short hb[4], lb[4];
#pragma unroll
        for (int j = 0; j < 4; ++j) {
            s = fmaf(f[j], f[j], s);
            hb[j] = bf16_rne(f[j]);
            lb[j] = bf16_rne(f[j] - bf16_to_f32(hb[j]));
        }
        *(ushort4*)(ehi + (size_t)code * D_DIM + c) = make_ushort4(hb[0], hb[1], hb[2], hb[3]);
        *(ushort4*)(elo + (size_t)code * D_DIM + c) = make_ushort4(lb[0], lb[1], lb[2], lb[3]);
    }
#pragma unroll
    for (int off = 32; off > 0; off >>= 1) s += __shfl_xor(s, off, 64);
    if (lane == 0) e2[code] = s;
}

// ---------------- fused split-GEMM + per-tile argmin ----------------------
__global__ __launch_bounds__(256, 2) void vq_gemm(
    const float* __restrict__ z, const unsigned short* __restrict__ ehi,
    const unsigned short* __restrict__ elo, const float* __restrict__ e2,
    float* __restrict__ pv, float* __restrict__ pif) {
    __shared__ __align__(16) char lds[(BM + BN) * LDSB];
    char* As = lds;                // [128 rows][64 effcols: hi(32)|lo(32)] +pad
    char* Bs = lds + BM * LDSB;

    const int t = threadIdx.x;
    const int bid = blockIdx.x;
    const int ntile = bid >> 8;    // 0..7   (consecutive blocks share B-tile)
    const int mtile = bid & 255;   // 0..255
    const int row0 = mtile * BM;
    const int c0g  = ntile * BN;

    // A staging: f4-id = p*256+t -> row=(id>>3), f4col=id&7
    const int ar = t >> 3;         // +32p
    const int ac = t & 7;
    // B staging: code = t>>1, chunks (t&1)*2 + {0,1}  (8 bf16 = 16B each)
    const int bc  = t >> 1;
    const int bq0 = (t & 1) * 2;

    const int wv = t >> 6, lane = t & 63;
    const int wr = wv >> 1, wc = wv & 1;
    const int lm = lane & 15, lk = lane >> 4;

    f32x4 acc[4][4];
    const f32x4 zero4 = {0.f, 0.f, 0.f, 0.f};
#pragma unroll
    for (int i = 0; i < 4; ++i)
#pragma unroll
        for (int j = 0; j < 4; ++j) acc[i][j] = zero4;

    float4 aReg[4];
    uint4  bhReg[2], blReg[2];

    auto stage_load = [&](int kt) {
        const int k0 = kt * BKP;
#pragma unroll
        for (int p = 0; p < 4; ++p)
            aReg[p] = *(const float4*)(z + (size_t)(row0 + ar + 32 * p) * D_DIM + k0 + ac * 4);
#pragma unroll
        for (int q = 0; q < 2; ++q) {
            const int ch = bq0 + q;
            bhReg[q] = *(const uint4*)(ehi + (size_t)(c0g + bc) * D_DIM + k0 + ch * 8);
            blReg[q] = *(const uint4*)(elo + (size_t)(c0g + bc) * D_DIM + k0 + ch * 8);
        }
    };
    auto stage_write = [&]() {
#pragma unroll
        for (int p = 0; p < 4; ++p) {
            char* rowp = As + (ar + 32 * p) * LDSB;
            float f[4] = {aReg[p].x, aReg[p].y, aReg[p].z, aReg[p].w};
            unsigned short hb[4], lb[4];
#pragma unroll
            for (int j = 0; j < 4; ++j) {
                hb[j] = bf16_rne(f[j]);
                lb[j] = bf16_rne(f[j] - bf16_to_f32(hb[j]));
            }
            *(ushort4*)(rowp + ac * 8)      = make_ushort4(hb[0], hb[1], hb[2], hb[3]);
            *(ushort4*)(rowp + 64 + ac * 8) = make_ushort4(lb[0], lb[1], lb[2], lb[3]);
        }
#pragma unroll
        for (int q = 0; q < 2; ++q) {
            const int ch = bq0 + q;
            char* rowp = Bs + bc * LDSB;
            *(uint4*)(rowp + ch * 16)      = bhReg[q];
            *(uint4*)(rowp + 64 + ch * 16) = blReg[q];
        }
    };
    // 3 k-steps per tile: (Ahi,Bhi), (Ahi,Blo), (Alo,Bhi) via independent offsets
    auto compute = [&]() {
        const int sA[3] = {0, 0, 64};
        const int sB[3] = {0, 64, 0};
#pragma unroll
        for (int s = 0; s < 3; ++s) {
            bf16x8 af[4], bfr[4];
#pragma unroll
            for (int mi = 0; mi < 4; ++mi) {
                const int r = wr * 64 + mi * 16 + lm;
                af[mi] = *(const bf16x8*)(As + r * LDSB + sA[s] + lk * 16);
            }
#pragma unroll
            for (int nj = 0; nj < 4; ++nj) {
                const int c = wc * 64 + nj * 16 + lm;
                bfr[nj] = *(const bf16x8*)(Bs + c * LDSB + sB[s] + lk * 16);
            }
#pragma unroll
            for (int mi = 0; mi < 4; ++mi)
#pragma unroll
                for (int nj = 0; nj < 4; ++nj)
                    acc[mi][nj] = __builtin_amdgcn_mfma_f32_16x16x32_bf16(
                        af[mi], bfr[nj], acc[mi][nj], 0, 0, 0);
        }
    };

    stage_load(0);
    stage_write();
    for (int kt = 0; kt < NKT; ++kt) {
        __syncthreads();                       // LDS writes visible
        if (kt + 1 < NKT) stage_load(kt + 1);  // issue next-tile loads early
        compute();                             // 48 MFMA
        __syncthreads();                       // reads done before overwrite
        if (kt + 1 < NKT) stage_write();
    }

    // ---- epilogue: score + per-row argmin over this 128-code tile ----
    // D mapping (16x16x32 bf16, m89-verified): col=lane&15, row=(lane>>4)*4+reg
    float best[16], bidx[16];
#pragma unroll
    for (int i = 0; i < 16; ++i) { best[i] = INFINITY; bidx[i] = 0.f; }
#pragma unroll
    for (int nj = 0; nj < 4; ++nj) {
        const int cloc = wc * 64 + nj * 16 + lm;
        const float e2v = e2[c0g + cloc];
#pragma unroll
        for (int mi = 0; mi < 4; ++mi)
#pragma unroll
            for (int r = 0; r < 4; ++r) {
                const float sc = fmaf(-2.0f, acc[mi][nj][r], e2v);
                const int bi = mi * 4 + r;
                if (sc < best[bi]) { best[bi] = sc; bidx[bi] = (float)(c0g + cloc); }
            }
    }
    // reduce across the 16 lanes (lm) sharing the same rows; lexicographic
#pragma unroll
    for (int off = 1; off < 16; off <<= 1) {
#pragma unroll
        for (int bi = 0; bi < 16; ++bi) {
            float v2 = __shfl_xor(best[bi], off, 64);
            float i2 = __shfl_xor(bidx[bi], off, 64);
            if (v2 < best[bi] || (v2 == best[bi] && i2 < bidx[bi])) {
                best[bi] = v2; bidx[bi] = i2;
            }
        }
    }
    __syncthreads();                 // done with GEMM LDS; reuse for reduction
    float* sv = (float*)lds;         // [2][128]
    float* si = sv + 256;
    if (lm == 0) {
#pragma unroll
        for (int mi = 0; mi < 4; ++mi)
#pragma unroll
            for (int r = 0; r < 4; ++r) {
                const int rl = wr * 64 + mi * 16 + lk * 4 + r;
                sv[wc * 128 + rl] = best[mi * 4 + r];
                si[wc * 128 + rl] = bidx[mi * 4 + r];
            }
    }
    __syncthreads();
    if (t < 128) {
        float v0 = sv[t], i0 = si[t];
        float v1 = sv[128 + t], i1 = si[128 + t];
        if (v1 < v0 || (v1 == v0 && i1 < i0)) { v0 = v1; i0 = i1; }
        pv [(size_t)ntile * N_TOK + row0 + t] = v0;
        pif[(size_t)ntile * N_TOK + row0 + t] = i0;
    }
}

// ---------------- final argmin across the 8 n-tiles -----------------------
__global__ __launch_bounds__(256) void vq_reduce(const float* __restrict__ pv,
                                                 const float* __restrict__ pif,
                                                 float* __restrict__ indf) {
    const int row = blockIdx.x * 256 + threadIdx.x;   // grid 128
    float v = pv[row], ix = pif[row];
#pragma unroll
    for (int nb = 1; nb < 8; ++nb) {
        float v2 = pv[(size_t)nb * N_TOK + row];
        float i2 = pif[(size_t)nb * N_TOK + row];
        if (v2 < v || (v2 == v && i2 < ix)) { v = v2; ix = i2; }
    }
    indf[row] = ix;
}

// ---------------- outputs: z_q, diff --------------------------------------
__global__ __launch_bounds__(256) void vq_out_kernel(
    const float* __restrict__ z, const float* __restrict__ ew,
    const float* __restrict__ indf, float* __restrict__ zq,
    float* __restrict__ diff) {
    const int w    = threadIdx.x >> 6;
    const int lane = threadIdx.x & 63;
    const int row  = blockIdx.x * 4 + w;
    const int c    = (int)indf[row];

    const float4* z4 = (const float4*)&z[(size_t)row * D_DIM];
    const float4* e4 = (const float4*)&ew[(size_t)c * D_DIM];
    float4* q4 = (float4*)&zq[(size_t)row * D_DIM];
    float4* d4 = (float4*)&diff[(size_t)row * D_DIM];

#pragma unroll
    for (int v = 0; v < 2; ++v) {
        const int i = v * 64 + lane;
        const float4 zv = z4[i];
        const float4 ev = e4[i];
        float4 qv, dv;
        float ax = ev.x - zv.x, ay = ev.y - zv.y, az = ev.z - zv.z, aw = ev.w - zv.w;
        qv.x = zv.x + ax; qv.y = zv.y + ay; qv.z = zv.z + az; qv.w = zv.w + aw;
        dv.x = 0.5f * (ax * ax); dv.y = 0.5f * (ay * ay);
        dv.z = 0.5f * (az * az); dv.w = 0.5f * (aw * aw);
        q4[i] = qv;
        d4[i] = dv;
    }
}

extern "C" void kernel_launch(void* const* d_in, const int* in_sizes, int n_in,
                              void* d_out, int out_size, void* d_ws, size_t ws_size,
                              hipStream_t stream) {
    const float* z  = (const float*)d_in[0];
    const float* ew = (const float*)d_in[1];
    float* out  = (float*)d_out;
    float* zq   = out;
    float* diff = out + (size_t)N_TOK * D_DIM;
    float* indf = out + (size_t)2 * N_TOK * D_DIM;

    // scratch inside the z_q region (64 MB; we use ~4.1 MB), overwritten last
    char* scratch = (char*)d_out;
    unsigned short* ehi = (unsigned short*)(scratch);                  // 1 MB
    unsigned short* elo = (unsigned short*)(scratch + (1u << 20));     // 1 MB
    float* e2  = (float*)(scratch + (2u << 20));                       // 4 KB
    float* pv  = (float*)(scratch + (2u << 20) + 4096);                // 1 MB
    float* pif = (float*)(scratch + (3u << 20) + 4096);                // 1 MB

    hipLaunchKernelGGL(vq_prep,   dim3(K_CODES / 4), dim3(256), 0, stream, ew, ehi, elo, e2);
    hipLaunchKernelGGL(vq_gemm,   dim3(2048),        dim3(256), 0, stream, z, ehi, elo, e2, pv, pif);
    hipLaunchKernelGGL(vq_reduce, dim3(N_TOK / 256), dim3(256), 0, stream, pv, pif, indf);
    hipLaunchKernelGGL(vq_out_kernel, dim3(N_TOK / 4), dim3(256), 0, stream, z, ew, indf, zq, diff);
}

// Round 4
// 196.898 us; speedup vs baseline: 3.1910x; 1.2051x over previous
//
#include <hip/hip_runtime.h>
#include <math.h>

// VQ-VAE quantize: z [8,4096,512] f32, embed_w [1024,512] f32
// out = concat(z_q, diff, ind-as-f32)
//
// bf16 split-precision MFMA:  dot ~= zhi*ehi + zhi*elo + zlo*ehi
// score = ||e||^2 - 2*dot  (row-constant ||z||^2 dropped; argmin invariant)
// zhi/zlo/ehi/elo precomputed bf16 planes -> gemm stages via global_load_lds.
// Scratch lives inside d_out (zq+diff regions), overwritten by the last kernel.

#define D_DIM   512
#define K_CODES 1024
#define N_TOK   32768

#define BM 128
#define BN 128
#define NKT 16            // 512 / 32 bf16-cols per k-tile

typedef __attribute__((ext_vector_type(8))) short bf16x8;
typedef __attribute__((ext_vector_type(4))) float f32x4;

__device__ __forceinline__ unsigned short bf16_rne(float f) {
    unsigned int u = __float_as_uint(f);
    return (unsigned short)((u + 0x7FFFu + ((u >> 16) & 1u)) >> 16);
}
__device__ __forceinline__ float bf16_to_f32(unsigned short b) {
    return __uint_as_float(((unsigned int)b) << 16);
}

#define GLOAD16(gp, lp)                                                        \
    __builtin_amdgcn_global_load_lds(                                          \
        (const __attribute__((address_space(1))) void*)(gp),                   \
        (__attribute__((address_space(3))) void*)(lp), 16, 0, 0)

// ---------------- z -> zhi/zlo bf16 planes --------------------------------
__global__ __launch_bounds__(256) void vq_zsplit(const float* __restrict__ z,
                                                 unsigned short* __restrict__ zhi,
                                                 unsigned short* __restrict__ zlo) {
    const int tid = blockIdx.x * 256 + threadIdx.x;   // grid 2048 -> 524288 thr
    const float4* z4 = (const float4*)z;
    ushort4* h4 = (ushort4*)zhi;
    ushort4* l4 = (ushort4*)zlo;
#pragma unroll
    for (int g = 0; g < 8; ++g) {
        const size_t i = (size_t)g * 524288 + tid;    // 4.19M float4 total
        float4 v = z4[i];
        float f[4] = {v.x, v.y, v.z, v.w};
        unsigned short hb[4], lb[4];
#pragma unroll
        for (int j = 0; j < 4; ++j) {
            hb[j] = bf16_rne(f[j]);
            lb[j] = bf16_rne(f[j] - bf16_to_f32(hb[j]));
        }
        h4[i] = make_ushort4(hb[0], hb[1], hb[2], hb[3]);
        l4[i] = make_ushort4(lb[0], lb[1], lb[2], lb[3]);
    }
}

// ---------------- ew -> ehi/elo bf16 + e2 ---------------------------------
__global__ __launch_bounds__(256) void vq_prep(const float* __restrict__ ew,
                                               unsigned short* __restrict__ ehi,
                                               unsigned short* __restrict__ elo,
                                               float* __restrict__ e2) {
    const int wv = threadIdx.x >> 6, lane = threadIdx.x & 63;
    const int code = blockIdx.x * 4 + wv;          // grid 256
    const float* row = ew + (size_t)code * D_DIM;
    float s = 0.0f;
#pragma unroll
    for (int h = 0; h < 2; ++h) {
        const int c = h * 256 + lane * 4;
        float4 v = *(const float4*)(row + c);
        float f[4] = {v.x, v.y, v.z, v.w};
        unsigned short hb[4], lb[4];
#pragma unroll
        for (int j = 0; j < 4; ++j) {
            s = fmaf(f[j], f[j], s);
            hb[j] = bf16_rne(f[j]);
            lb[j] = bf16_rne(f[j] - bf16_to_f32(hb[j]));
        }
        *(ushort4*)(ehi + (size_t)code * D_DIM + c) = make_ushort4(hb[0], hb[1], hb[2], hb[3]);
        *(ushort4*)(elo + (size_t)code * D_DIM + c) = make_ushort4(lb[0], lb[1], lb[2], lb[3]);
    }
#pragma unroll
    for (int off = 32; off > 0; off >>= 1) s += __shfl_xor(s, off, 64);
    if (lane == 0) e2[code] = s;
}

// ---------------- split-GEMM + per-tile argmin (global_load_lds) ----------
__global__ __launch_bounds__(256, 3) void vq_gemm(
    const unsigned short* __restrict__ zhi, const unsigned short* __restrict__ zlo,
    const unsigned short* __restrict__ ehi, const unsigned short* __restrict__ elo,
    const float* __restrict__ e2, float* __restrict__ pv, float* __restrict__ pif) {
    // 32 KB: 4 planes x [4 kchunks][128 rows] x 16B, linear (gload_lds needs it)
    __shared__ __align__(16) unsigned short lds[16384];
    const int AHI = 0, ALO = 4096, BHI = 8192, BLO = 12288;  // ushort offsets

    const int t = threadIdx.x, lane = t & 63, wv = t >> 6;
    // XCD-contiguous swizzle: 2048 wgs, 8 XCDs, 256 each; ntile innermost
    const int b  = blockIdx.x;
    const int wg = (b & 7) * 256 + (b >> 3);
    const int mtile = wg >> 3, ntile = wg & 7;
    const int row0 = mtile * BM;
    const int c0g  = ntile * BN;

    // staging: per wave 2 instrs/plane; 16B-slot idx = (wv*2+i)*64+lane
    const int idx0 = (wv * 2 + 0) * 64 + lane;
    const int idx1 = (wv * 2 + 1) * 64 + lane;
    const int c_0 = idx0 >> 7, r_0 = idx0 & 127;   // kchunk, row-in-tile
    const int c_1 = idx1 >> 7, r_1 = idx1 & 127;
    const size_t zo0 = (size_t)(row0 + r_0) * D_DIM + c_0 * 8;
    const size_t zo1 = (size_t)(row0 + r_1) * D_DIM + c_1 * 8;
    const size_t eo0 = (size_t)(c0g + r_0) * D_DIM + c_0 * 8;
    const size_t eo1 = (size_t)(c0g + r_1) * D_DIM + c_1 * 8;
    const int l0 = (wv * 2 + 0) * 512;   // ushort base of instr 0 chunk
    const int l1 = (wv * 2 + 1) * 512;

    const int wr = wv >> 1, wc = wv & 1;
    const int lm = lane & 15, lk = lane >> 4;

    f32x4 acc[4][4];
    const f32x4 zero4 = {0.f, 0.f, 0.f, 0.f};
#pragma unroll
    for (int i = 0; i < 4; ++i)
#pragma unroll
        for (int j = 0; j < 4; ++j) acc[i][j] = zero4;

    for (int kt = 0; kt < NKT; ++kt) {
        const int ko = kt * 32;           // bf16-cols consumed per tile
        GLOAD16(zhi + zo0 + ko, &lds[AHI + l0]);
        GLOAD16(zhi + zo1 + ko, &lds[AHI + l1]);
        GLOAD16(zlo + zo0 + ko, &lds[ALO + l0]);
        GLOAD16(zlo + zo1 + ko, &lds[ALO + l1]);
        GLOAD16(ehi + eo0 + ko, &lds[BHI + l0]);
        GLOAD16(ehi + eo1 + ko, &lds[BHI + l1]);
        GLOAD16(elo + eo0 + ko, &lds[BLO + l0]);
        GLOAD16(elo + eo1 + ko, &lds[BLO + l1]);
        __syncthreads();                  // drains vmcnt before reads

        bf16x8 ah[4], al[4], bh[4], bl[4];
#pragma unroll
        for (int mi = 0; mi < 4; ++mi) {
            const int s = (lk * 128 + wr * 64 + mi * 16 + lm) * 8;
            ah[mi] = *(const bf16x8*)&lds[AHI + s];
            al[mi] = *(const bf16x8*)&lds[ALO + s];
        }
#pragma unroll
        for (int nj = 0; nj < 4; ++nj) {
            const int s = (lk * 128 + wc * 64 + nj * 16 + lm) * 8;
            bh[nj] = *(const bf16x8*)&lds[BHI + s];
            bl[nj] = *(const bf16x8*)&lds[BLO + s];
        }
#pragma unroll
        for (int mi = 0; mi < 4; ++mi)
#pragma unroll
            for (int nj = 0; nj < 4; ++nj)
                acc[mi][nj] = __builtin_amdgcn_mfma_f32_16x16x32_bf16(
                    ah[mi], bh[nj], acc[mi][nj], 0, 0, 0);
#pragma unroll
        for (int mi = 0; mi < 4; ++mi)
#pragma unroll
            for (int nj = 0; nj < 4; ++nj)
                acc[mi][nj] = __builtin_amdgcn_mfma_f32_16x16x32_bf16(
                    ah[mi], bl[nj], acc[mi][nj], 0, 0, 0);
#pragma unroll
        for (int mi = 0; mi < 4; ++mi)
#pragma unroll
            for (int nj = 0; nj < 4; ++nj)
                acc[mi][nj] = __builtin_amdgcn_mfma_f32_16x16x32_bf16(
                    al[mi], bh[nj], acc[mi][nj], 0, 0, 0);
        __syncthreads();                  // reads done before next overwrite
    }

    // ---- epilogue: score + per-row argmin over this 128-code tile ----
    // D mapping (16x16x32 bf16): col=lane&15 (code), row=(lane>>4)*4+reg (z-row)
    float best[16], bidx[16];
#pragma unroll
    for (int i = 0; i < 16; ++i) { best[i] = INFINITY; bidx[i] = 0.f; }
#pragma unroll
    for (int nj = 0; nj < 4; ++nj) {
        const int cloc = wc * 64 + nj * 16 + lm;
        const float e2v = e2[c0g + cloc];
#pragma unroll
        for (int mi = 0; mi < 4; ++mi)
#pragma unroll
            for (int r = 0; r < 4; ++r) {
                const float sc = fmaf(-2.0f, acc[mi][nj][r], e2v);
                const int bi = mi * 4 + r;
                if (sc < best[bi]) { best[bi] = sc; bidx[bi] = (float)(c0g + cloc); }
            }
    }
#pragma unroll
    for (int off = 1; off < 16; off <<= 1) {
#pragma unroll
        for (int bi = 0; bi < 16; ++bi) {
            float v2 = __shfl_xor(best[bi], off, 64);
            float i2 = __shfl_xor(bidx[bi], off, 64);
            if (v2 < best[bi] || (v2 == best[bi] && i2 < bidx[bi])) {
                best[bi] = v2; bidx[bi] = i2;
            }
        }
    }
    __syncthreads();                 // LDS free; reuse for cross-wave reduce
    float* sv = (float*)lds;         // [2][128]
    float* si = sv + 256;
    if (lm == 0) {
#pragma unroll
        for (int mi = 0; mi < 4; ++mi)
#pragma unroll
            for (int r = 0; r < 4; ++r) {
                const int rl = wr * 64 + mi * 16 + lk * 4 + r;
                sv[wc * 128 + rl] = best[mi * 4 + r];
                si[wc * 128 + rl] = bidx[mi * 4 + r];
            }
    }
    __syncthreads();
    if (t < 128) {
        float v0 = sv[t], i0 = si[t];
        float v1 = sv[128 + t], i1 = si[128 + t];
        if (v1 < v0 || (v1 == v0 && i1 < i0)) { v0 = v1; i0 = i1; }
        pv [(size_t)ntile * N_TOK + row0 + t] = v0;
        pif[(size_t)ntile * N_TOK + row0 + t] = i0;
    }
}

// ---------------- final argmin across the 8 n-tiles -----------------------
__global__ __launch_bounds__(256) void vq_reduce(const float* __restrict__ pv,
                                                 const float* __restrict__ pif,
                                                 float* __restrict__ indf) {
    const int row = blockIdx.x * 256 + threadIdx.x;   // grid 128
    float v = pv[row], ix = pif[row];
#pragma unroll
    for (int nb = 1; nb < 8; ++nb) {
        float v2 = pv[(size_t)nb * N_TOK + row];
        float i2 = pif[(size_t)nb * N_TOK + row];
        if (v2 < v || (v2 == v && i2 < ix)) { v = v2; ix = i2; }
    }
    indf[row] = ix;
}

// ---------------- outputs: z_q, diff --------------------------------------
__global__ __launch_bounds__(256) void vq_out_kernel(
    const float* __restrict__ z, const float* __restrict__ ew,
    const float* __restrict__ indf, float* __restrict__ zq,
    float* __restrict__ diff) {
    const int w    = threadIdx.x >> 6;
    const int lane = threadIdx.x & 63;
    const int row  = blockIdx.x * 4 + w;
    const int c    = (int)indf[row];

    const float4* z4 = (const float4*)&z[(size_t)row * D_DIM];
    const float4* e4 = (const float4*)&ew[(size_t)c * D_DIM];
    float4* q4 = (float4*)&zq[(size_t)row * D_DIM];
    float4* d4 = (float4*)&diff[(size_t)row * D_DIM];

#pragma unroll
    for (int v = 0; v < 2; ++v) {
        const int i = v * 64 + lane;
        const float4 zv = z4[i];
        const float4 ev = e4[i];
        float4 qv, dv;
        float ax = ev.x - zv.x, ay = ev.y - zv.y, az = ev.z - zv.z, aw = ev.w - zv.w;
        qv.x = zv.x + ax; qv.y = zv.y + ay; qv.z = zv.z + az; qv.w = zv.w + aw;
        dv.x = 0.5f * (ax * ax); dv.y = 0.5f * (ay * ay);
        dv.z = 0.5f * (az * az); dv.w = 0.5f * (aw * aw);
        q4[i] = qv;
        d4[i] = dv;
    }
}

extern "C" void kernel_launch(void* const* d_in, const int* in_sizes, int n_in,
                              void* d_out, int out_size, void* d_ws, size_t ws_size,
                              hipStream_t stream) {
    const float* z  = (const float*)d_in[0];
    const float* ew = (const float*)d_in[1];
    float* out  = (float*)d_out;
    float* zq   = out;
    float* diff = out + (size_t)N_TOK * D_DIM;
    float* indf = out + (size_t)2 * N_TOK * D_DIM;

    // scratch in zq region (~4.1 MB) + diff region (64 MB for zhi/zlo);
    // both regions are rewritten by vq_out_kernel at the end.
    char* s0 = (char*)d_out;
    unsigned short* ehi = (unsigned short*)(s0);                   // 1 MB
    unsigned short* elo = (unsigned short*)(s0 + (1u << 20));      // 1 MB
    float* e2  = (float*)(s0 + (2u << 20));                        // 4 KB
    float* pv  = (float*)(s0 + (2u << 20) + 4096);                 // 1 MB
    float* pif = (float*)(s0 + (3u << 20) + 4096);                 // 1 MB
    unsigned short* zhi = (unsigned short*)diff;                   // 32 MB
    unsigned short* zlo = zhi + (size_t)N_TOK * D_DIM;             // 32 MB

    hipLaunchKernelGGL(vq_zsplit, dim3(2048),       dim3(256), 0, stream, z, zhi, zlo);
    hipLaunchKernelGGL(vq_prep,   dim3(K_CODES / 4), dim3(256), 0, stream, ew, ehi, elo, e2);
    hipLaunchKernelGGL(vq_gemm,   dim3(2048),       dim3(256), 0, stream,
                       zhi, zlo, ehi, elo, e2, pv, pif);
    hipLaunchKernelGGL(vq_reduce, dim3(N_TOK / 256), dim3(256), 0, stream, pv, pif, indf);
    hipLaunchKernelGGL(vq_out_kernel, dim3(N_TOK / 4), dim3(256), 0, stream,
                       z, ew, indf, zq, diff);
}